// Round 2
// baseline (1733.727 us; speedup 1.0000x reference)
//
#include <hip/hip_runtime.h>

// GPUHungarianMatcher: exact replication of the reference's _lsa variant.
// NOTE: the reference's "JV" has minv reset every inner iteration (minv1 is a
// copy of a never-updated INF array), so it is a chain-Dijkstra variant:
//   each step: val_j = cost(i0,j) - u[i0] - v[j] fresh over unused j,
//   j1 = argmin (first occurrence), way[j1] = j0, u[p[used]] += d, v[used] -= d.
// We replicate that exactly (fp32 cost, fp64 potentials, same associativity,
// same tie-break), one block per batch.

constexpr int B = 8;
constexpr int Q = 2048;   // columns (queries)
constexpr int T = 256;    // rows (targets)
constexpr int NT = 256;   // threads per block
constexpr int KPT = Q / NT;  // 8 columns per thread, j = 1 + tid + k*NT
constexpr int NW = NT / 64;
constexpr double DINF = 1e300;

__launch_bounds__(NT, 1)
__global__ void hungarian_kernel(const float* __restrict__ outs,
                                 const float* __restrict__ tgts,
                                 int* __restrict__ out) {
  const int b = blockIdx.x;
  const int tid = threadIdx.x;

  __shared__ float tx[T], ty[T];
  __shared__ double u[T + 1];     // row potentials (rows = targets)
  __shared__ short p[Q + 1];      // p[j] = row matched to column j (1-based), 0 free
  __shared__ short way[Q + 1];    // chain: way[j1] = previous j0 (set at selection)
  __shared__ double s_rv[NW];
  __shared__ int s_ri[NW];
  __shared__ int ansArr[T];
  __shared__ int sh_j0;
  __shared__ int sh_brk;
  __shared__ double sh_delta;
  __shared__ float sh_f;

  const size_t qbase = (size_t)b * Q;
  const size_t tbase = (size_t)b * T;

  // ---- stage per-thread column data (fixed mapping j = 1 + tid + k*NT) ----
  float xs[KPT], qx[KPT], qy[KPT];
#pragma unroll
  for (int k = 0; k < KPT; ++k) {
    const size_t o = (qbase + tid + k * NT) * 3;
    xs[k] = outs[o];
    qx[k] = outs[o + 1];
    qy[k] = outs[o + 2];
  }
  {
    const size_t o = (tbase + tid) * 3;   // T == NT
    tx[tid] = tgts[o + 1];
    ty[tid] = tgts[o + 2];
  }

  // ---- softmax over Q logits (fp32, subtract max) ----
  float lmax = xs[0];
#pragma unroll
  for (int k = 1; k < KPT; ++k) lmax = fmaxf(lmax, xs[k]);
  for (int off = 32; off > 0; off >>= 1) lmax = fmaxf(lmax, __shfl_down(lmax, off));
  if ((tid & 63) == 0) s_rv[tid >> 6] = (double)lmax;
  __syncthreads();
  if (tid == 0) {
    float m2 = (float)s_rv[0];
    for (int w = 1; w < NW; ++w) m2 = fmaxf(m2, (float)s_rv[w]);
    sh_f = m2;
  }
  __syncthreads();
  const float smax = sh_f;
  float ex[KPT];
  float lsum = 0.f;
#pragma unroll
  for (int k = 0; k < KPT; ++k) { ex[k] = expf(xs[k] - smax); lsum += ex[k]; }
  for (int off = 32; off > 0; off >>= 1) lsum += __shfl_down(lsum, off);
  if ((tid & 63) == 0) s_rv[tid >> 6] = (double)lsum;
  __syncthreads();
  if (tid == 0) {
    float s2 = 0.f;
    for (int w = 0; w < NW; ++w) s2 += (float)s_rv[w];
    sh_f = s2;
  }
  __syncthreads();
  const float ssum = sh_f;
  float np_[KPT];
#pragma unroll
  for (int k = 0; k < KPT; ++k) np_[k] = -(ex[k] / ssum);

  // ---- init state ----
  for (int j = tid; j <= Q; j += NT) p[j] = 0;
  for (int r = tid; r <= T; r += NT) u[r] = 0.0;
  double vreg[KPT];           // v[j] for this thread's columns
#pragma unroll
  for (int k = 0; k < KPT; ++k) vreg[k] = 0.0;
  __syncthreads();

  // ---- main loop over rows ----
  for (int i = 1; i <= T; ++i) {
    if (tid == 0) { p[0] = (short)i; sh_j0 = 0; }
    unsigned usedMask = 0;
    int rowHold[KPT];         // matched row of each of my used columns
#pragma unroll
    for (int k = 0; k < KPT; ++k) rowHold[k] = 0;
    __syncthreads();          // B0: p[0], sh_j0 visible; prev-row u/p writes drained

    for (;;) {
      const int j0 = sh_j0;
      const int i0 = (int)p[j0];
      const double ui0 = u[i0];
      const float tX = tx[i0 - 1];
      const float tY = ty[i0 - 1];

      // mark j0 used (owner thread), remember its matched row
      if (j0 > 0) {
#pragma unroll
        for (int k = 0; k < KPT; ++k) {
          if (j0 == 1 + tid + k * NT) { usedMask |= 1u << k; rowHold[k] = i0; }
        }
      }

      // fresh reduced costs over unused columns; local argmin (ascending j)
      double bval = DINF;
      int bidx = Q + 2;
#pragma unroll
      for (int k = 0; k < KPT; ++k) {
        if (!(usedMask & (1u << k))) {
          const float cf = fabsf(qx[k] - tX) + fabsf(qy[k] - tY) + np_[k];
          const double cur = ((double)cf - ui0) - vreg[k];
          if (cur < bval) { bval = cur; bidx = 1 + tid + k * NT; }
        }
      }
      // wave argmin (lexicographic: value, then smallest j)
      for (int off = 32; off > 0; off >>= 1) {
        const double ov = __shfl_down(bval, off);
        const int oi = __shfl_down(bidx, off);
        if (ov < bval || (ov == bval && oi < bidx)) { bval = ov; bidx = oi; }
      }
      if ((tid & 63) == 0) { s_rv[tid >> 6] = bval; s_ri[tid >> 6] = bidx; }
      __syncthreads();        // B1
      if (tid == 0) {
        double dv = s_rv[0]; int di = s_ri[0];
        for (int w = 1; w < NW; ++w) {
          if (s_rv[w] < dv || (s_rv[w] == dv && s_ri[w] < di)) { dv = s_rv[w]; di = s_ri[w]; }
        }
        way[di] = (short)sh_j0;   // way[j1] = previous j0 (only selection matters)
        sh_delta = dv;
        sh_brk = ((int)p[di] == 0);
        sh_j0 = di;
      }
      __syncthreads();        // B2
      const double delta = sh_delta;

      // u[p[used]] += delta; v[used] -= delta  (used = my marked columns + j=0)
#pragma unroll
      for (int k = 0; k < KPT; ++k) {
        if (usedMask & (1u << k)) { vreg[k] -= delta; u[rowHold[k]] += delta; }
      }
      if (tid == 0) u[i] += delta;   // j = 0: p[0] = i

      if (sh_brk) break;      // sh_brk stable until thread 0's next B1->B2 window
    }

    // augment along the visit chain (thread 0 only; others don't touch p until B0)
    if (tid == 0) {
      int j0a = sh_j0;
      while (j0a) { const int jp = (int)way[j0a]; p[j0a] = p[jp]; j0a = jp; }
    }
  }
  __syncthreads();

  // ---- extract assignment, rank-sort (values distinct), write int32 ----
  for (int j = 1 + tid; j <= Q; j += NT) {
    const int pi = (int)p[j];
    if (pi > 0) ansArr[pi - 1] = j - 1;
  }
  __syncthreads();
  const int a = ansArr[tid];
  int rank = 0;
  for (int t2 = 0; t2 < T; ++t2) rank += (ansArr[t2] < a) ? 1 : 0;
  out[(size_t)b * T + rank] = a;                      // row_ind (sorted query idx)
  out[(size_t)B * T + (size_t)b * T + rank] = tid;    // col_ind (target idx)
}

extern "C" void kernel_launch(void* const* d_in, const int* in_sizes, int n_in,
                              void* d_out, int out_size, void* d_ws, size_t ws_size,
                              hipStream_t stream) {
  const float* outs = (const float*)d_in[0];   // (8, 2048, 3) fp32
  const float* tgts = (const float*)d_in[1];   // (8, 256, 3) fp32
  int* out = (int*)d_out;                      // row_ind (8,256) ++ col_ind (8,256)
  hungarian_kernel<<<B, NT, 0, stream>>>(outs, tgts, out);
}